// Round 1
// baseline (554.995 us; speedup 1.0000x reference)
//
#include <hip/hip_runtime.h>

// 2-layer GCN, factored form:
//   dinv = rsqrt(1 + indeg)
//   g  = dinv[i] * (x[i] @ W1)            [N,32]
//   acc[i] = g[i] + sum_{e: dst=i} g[src] (self-loop = init with g[i])
//   h1 = relu(dinv[i]*acc[i] + b1)
//   s  = dinv[i] * (h1 . W2)              [N] scalar
//   acc2[i] = s[i] + sum_{e: dst=i} s[src]
//   out[i] = dinv[i]*acc2[i] + b2

__global__ void k_init_deg(float* __restrict__ deg, int n) {
    int i = blockIdx.x * blockDim.x + threadIdx.x;
    if (i < n) deg[i] = 1.0f;  // self-loop
}

__global__ void k_count_deg(const int* __restrict__ dst, float* __restrict__ deg, int e) {
    int i = blockIdx.x * blockDim.x + threadIdx.x;
    if (i < e) atomicAdd(&deg[dst[i]], 1.0f);
}

// one thread per (node i, feature j); j = t & 31
__global__ void k_node1(const float* __restrict__ x, const float* __restrict__ W1,
                        float* __restrict__ deg_dinv, float* __restrict__ g,
                        float* __restrict__ acc, int n) {
    int t = blockIdx.x * blockDim.x + threadIdx.x;
    if (t >= n * 32) return;
    int i = t >> 5, j = t & 31;
    float d = rsqrtf(deg_dinv[i]);          // deg >= 1 always
    float x0 = x[2 * i], x1 = x[2 * i + 1];
    float h = fmaf(x0, W1[j], x1 * W1[32 + j]);
    float gv = d * h;
    g[t] = gv;
    acc[t] = gv;                            // self-loop contribution
    if (j == 0) deg_dinv[i] = d;            // in-place deg -> dinv (same wave, read-before-write)
}

// one thread per (edge, feature j)
__global__ void k_scatter1(const int* __restrict__ src, const int* __restrict__ dst,
                           const float* __restrict__ g, float* __restrict__ acc, int e) {
    int t = blockIdx.x * blockDim.x + threadIdx.x;
    if (t >= e * 32) return;   // e*32 = 81.92M < 2^31
    int ed = t >> 5, j = t & 31;
    int s = src[ed], d = dst[ed];
    atomicAdd(&acc[d * 32 + j], g[s * 32 + j]);
}

// one thread per node: h1 = relu(dinv*acc + b1); s = dinv*(h1 . W2)
__global__ void k_node2(const float* __restrict__ acc, const float* __restrict__ dinv,
                        const float* __restrict__ b1, const float* __restrict__ W2,
                        float* __restrict__ s, float* __restrict__ acc2, int n) {
    int i = blockIdx.x * blockDim.x + threadIdx.x;
    if (i >= n) return;
    float d = dinv[i];
    float dot = 0.f;
#pragma unroll
    for (int j = 0; j < 32; ++j) {
        float h = fmaf(d, acc[i * 32 + j], b1[j]);
        h = fmaxf(h, 0.f);
        dot = fmaf(h, W2[j], dot);
    }
    float sv = d * dot;
    s[i] = sv;
    acc2[i] = sv;  // self-loop contribution
}

__global__ void k_scatter2(const int* __restrict__ src, const int* __restrict__ dst,
                           const float* __restrict__ s, float* __restrict__ acc2, int e) {
    int i = blockIdx.x * blockDim.x + threadIdx.x;
    if (i < e) atomicAdd(&acc2[dst[i]], s[src[i]]);
}

__global__ void k_out(const float* __restrict__ acc2, const float* __restrict__ dinv,
                      const float* __restrict__ b2, float* __restrict__ out, int n) {
    int i = blockIdx.x * blockDim.x + threadIdx.x;
    if (i < n) out[i] = dinv[i] * acc2[i] + b2[0];
}

extern "C" void kernel_launch(void* const* d_in, const int* in_sizes, int n_in,
                              void* d_out, int out_size, void* d_ws, size_t ws_size,
                              hipStream_t stream) {
    const float* x  = (const float*)d_in[0];
    const int*   ei = (const int*)d_in[1];
    const float* W1 = (const float*)d_in[2];
    const float* b1 = (const float*)d_in[3];
    const float* W2 = (const float*)d_in[4];
    const float* b2 = (const float*)d_in[5];
    float* out = (float*)d_out;

    int n = in_sizes[0] / 2;   // 100000
    int e = in_sizes[1] / 2;   // 2560000
    const int* src = ei;
    const int* dst = ei + e;

    // workspace layout (256B aligned)
    char* ws = (char*)d_ws;
    auto align = [](size_t v) { return (v + 255) & ~(size_t)255; };
    size_t off = 0;
    float* deg_dinv = (float*)(ws + off); off = align(off + (size_t)n * 4);
    float* g        = (float*)(ws + off); off = align(off + (size_t)n * 32 * 4);
    float* acc      = (float*)(ws + off); off = align(off + (size_t)n * 32 * 4);
    float* s        = (float*)(ws + off); off = align(off + (size_t)n * 4);
    float* acc2     = (float*)(ws + off); off = align(off + (size_t)n * 4);
    (void)ws_size;

    const int B = 256;
    k_init_deg<<<(n + B - 1) / B, B, 0, stream>>>(deg_dinv, n);
    k_count_deg<<<(e + B - 1) / B, B, 0, stream>>>(dst, deg_dinv, e);
    k_node1<<<(n * 32 + B - 1) / B, B, 0, stream>>>(x, W1, deg_dinv, g, acc, n);
    k_scatter1<<<(e * 32 + B - 1) / B, B, 0, stream>>>(src, dst, g, acc, e);
    k_node2<<<(n + B - 1) / B, B, 0, stream>>>(acc, deg_dinv, b1, W2, s, acc2, n);
    k_scatter2<<<(e + B - 1) / B, B, 0, stream>>>(src, dst, s, acc2, e);
    k_out<<<(n + B - 1) / B, B, 0, stream>>>(acc2, deg_dinv, b2, out, n);
}

// Round 2
// 515.546 us; speedup vs baseline: 1.0765x; 1.0765x over previous
//
#include <hip/hip_runtime.h>

// 2-layer GCN with rank-2 factorization of layer 1:
//   dinv = rsqrt(1 + indeg)
//   px[i] = dinv[i] * x[i]                         (float2)
//   P[i]  = sum_{e: dst=i} px[src]                 (float2 scatter, 8B/edge)
//   acc_j = (px[i]+P[i]) . W1[:,j]                 (rank-2: apply W1 AFTER aggregation)
//   h1_j  = relu(dinv[i]*acc_j + b1[j])
//   s[i]  = dinv[i] * (h1 . W2)                    (scalar per node)
//   S[i]  = s[i] + sum_{e: dst=i} s[src]           (scalar scatter, 4B/edge)
//   out[i]= dinv[i]*S[i] + b2

__global__ void k_zero(int* __restrict__ ideg, float2* __restrict__ P, int n) {
    int i = blockIdx.x * blockDim.x + threadIdx.x;
    if (i < n) { ideg[i] = 0; P[i] = make_float2(0.f, 0.f); }
}

__global__ void k_count(const int* __restrict__ dst, int* __restrict__ ideg, int e) {
    int i = blockIdx.x * blockDim.x + threadIdx.x;
    if (i < e) atomicAdd(&ideg[dst[i]], 1);
}

__global__ void k_px(const float2* __restrict__ x, const int* __restrict__ ideg,
                     float* __restrict__ dinv, float2* __restrict__ px, int n) {
    int i = blockIdx.x * blockDim.x + threadIdx.x;
    if (i >= n) return;
    float d = rsqrtf((float)(1 + ideg[i]));   // deg includes self-loop, always >= 1
    dinv[i] = d;
    float2 xv = x[i];
    px[i] = make_float2(d * xv.x, d * xv.y);
}

__global__ void k_scatter_px(const int* __restrict__ src, const int* __restrict__ dst,
                             const float2* __restrict__ px, float* __restrict__ Pf, int e) {
    int i = blockIdx.x * blockDim.x + threadIdx.x;
    if (i >= e) return;
    int s = src[i], d = dst[i];
    float2 v = px[s];
    atomicAdd(&Pf[2 * d],     v.x);
    atomicAdd(&Pf[2 * d + 1], v.y);
}

// per node: rank-2 reconstruction -> relu -> dot with W2 (all in registers)
__global__ void k_node(const float2* __restrict__ px, const float2* __restrict__ P,
                       const float* __restrict__ dinv,
                       const float* __restrict__ W1, const float* __restrict__ b1,
                       const float* __restrict__ W2,
                       float* __restrict__ s, float* __restrict__ S, int n) {
    int i = blockIdx.x * blockDim.x + threadIdx.x;
    if (i >= n) return;
    float d = dinv[i];
    float2 v = px[i], p = P[i];
    float ax = v.x + p.x, ay = v.y + p.y;
    float dot = 0.f;
#pragma unroll
    for (int j = 0; j < 32; ++j) {
        float acc = fmaf(ax, W1[j], ay * W1[32 + j]);
        float h = fmaxf(fmaf(d, acc, b1[j]), 0.f);
        dot = fmaf(h, W2[j], dot);
    }
    float sv = d * dot;
    s[i] = sv;
    S[i] = sv;   // self-loop contribution for layer 2
}

__global__ void k_scatter_s(const int* __restrict__ src, const int* __restrict__ dst,
                            const float* __restrict__ s, float* __restrict__ S, int e) {
    int i = blockIdx.x * blockDim.x + threadIdx.x;
    if (i < e) atomicAdd(&S[dst[i]], s[src[i]]);
}

__global__ void k_out(const float* __restrict__ S, const float* __restrict__ dinv,
                      const float* __restrict__ b2, float* __restrict__ out, int n) {
    int i = blockIdx.x * blockDim.x + threadIdx.x;
    if (i < n) out[i] = dinv[i] * S[i] + b2[0];
}

extern "C" void kernel_launch(void* const* d_in, const int* in_sizes, int n_in,
                              void* d_out, int out_size, void* d_ws, size_t ws_size,
                              hipStream_t stream) {
    const float* x  = (const float*)d_in[0];
    const int*   ei = (const int*)d_in[1];
    const float* W1 = (const float*)d_in[2];
    const float* b1 = (const float*)d_in[3];
    const float* W2 = (const float*)d_in[4];
    const float* b2 = (const float*)d_in[5];
    float* out = (float*)d_out;

    int n = in_sizes[0] / 2;   // 100000
    int e = in_sizes[1] / 2;   // 2560000
    const int* src = ei;
    const int* dst = ei + e;

    // workspace layout (256B aligned); total ~3.2MB
    char* ws = (char*)d_ws;
    auto align = [](size_t v) { return (v + 255) & ~(size_t)255; };
    size_t off = 0;
    int*    ideg = (int*)   (ws + off); off = align(off + (size_t)n * 4);
    float*  dinv = (float*) (ws + off); off = align(off + (size_t)n * 4);
    float2* px   = (float2*)(ws + off); off = align(off + (size_t)n * 8);
    float2* P    = (float2*)(ws + off); off = align(off + (size_t)n * 8);
    float*  s    = (float*) (ws + off); off = align(off + (size_t)n * 4);
    float*  S    = (float*) (ws + off); off = align(off + (size_t)n * 4);
    (void)ws_size;

    const int B = 256;
    int gn = (n + B - 1) / B, ge = (e + B - 1) / B;
    k_zero      <<<gn, B, 0, stream>>>(ideg, P, n);
    k_count     <<<ge, B, 0, stream>>>(dst, ideg, e);
    k_px        <<<gn, B, 0, stream>>>((const float2*)x, ideg, dinv, px, n);
    k_scatter_px<<<ge, B, 0, stream>>>(src, dst, px, (float*)P, e);
    k_node      <<<gn, B, 0, stream>>>(px, P, dinv, W1, b1, W2, s, S, n);
    k_scatter_s <<<ge, B, 0, stream>>>(src, dst, s, S, e);
    k_out       <<<gn, B, 0, stream>>>(S, dinv, b2, out, n);
}

// Round 3
// 135.176 us; speedup vs baseline: 4.1057x; 3.8139x over previous
//
#include <hip/hip_runtime.h>

// 2-layer GCN, rank-2 factorization + dst-range bucketing + LDS aggregation.
//   dinv = rsqrt(1 + indeg)
//   px[i] = dinv[i]*x[i]; P[i] = sum_{src->i} px[src]
//   h1 = relu(dinv*( (px+P) . W1 ) + b1); s = dinv*(h1.W2)
//   S[i] = s[i] + sum_{src->i} s[src]; out = dinv*S + b2
// Aggregations run per node-range in LDS (ds_add_f32), merged with coalesced
// global atomics -> avoids random-line atomic RMWs at the coherent point.

#define NR 16
#define RS_MAX 6400
#define AGG_BLKS 16
#define CHUNK 4096

// ---------------- shared small kernels ----------------

__global__ void k_px(const float2* __restrict__ x, const int* __restrict__ ideg,
                     float* __restrict__ dinv, float2* __restrict__ px, int n) {
    int i = blockIdx.x * blockDim.x + threadIdx.x;
    if (i >= n) return;
    float d = rsqrtf((float)(1 + ideg[i]));
    dinv[i] = d;
    float2 xv = x[i];
    px[i] = make_float2(d * xv.x, d * xv.y);
}

__global__ void k_node(const float2* __restrict__ px, const float2* __restrict__ P,
                       const float* __restrict__ dinv,
                       const float* __restrict__ W1, const float* __restrict__ b1,
                       const float* __restrict__ W2,
                       float* __restrict__ s, float* __restrict__ S, int n) {
    int i = blockIdx.x * blockDim.x + threadIdx.x;
    if (i >= n) return;
    float d = dinv[i];
    float2 v = px[i], p = P[i];
    float ax = v.x + p.x, ay = v.y + p.y;
    float dot = 0.f;
#pragma unroll
    for (int j = 0; j < 32; ++j) {
        float acc = fmaf(ax, W1[j], ay * W1[32 + j]);
        float h = fmaxf(fmaf(d, acc, b1[j]), 0.f);
        dot = fmaf(h, W2[j], dot);
    }
    float sv = d * dot;
    s[i] = sv;
    S[i] = sv;   // self-loop term for layer 2
}

__global__ void k_out(const float* __restrict__ S, const float* __restrict__ dinv,
                      const float* __restrict__ b2, float* __restrict__ out, int n) {
    int i = blockIdx.x * blockDim.x + threadIdx.x;
    if (i < n) out[i] = dinv[i] * S[i] + b2[0];
}

// ---------------- fast path: bucketed LDS aggregation ----------------

__global__ void k_init(int* __restrict__ ideg, float* __restrict__ Pf,
                       int* __restrict__ btot, int n) {
    int i = blockIdx.x * blockDim.x + threadIdx.x;
    if (i < n) { ideg[i] = 0; Pf[2 * i] = 0.f; Pf[2 * i + 1] = 0.f; }
    if (i < NR * 16) btot[i] = 0;
}

__global__ void k_bcount(const int* __restrict__ dst, int* __restrict__ btot,
                         int e, int rs) {
    __shared__ int h[NR];
    if (threadIdx.x < NR) h[threadIdx.x] = 0;
    __syncthreads();
    for (int i = blockIdx.x * blockDim.x + threadIdx.x; i < e; i += gridDim.x * blockDim.x)
        atomicAdd(&h[dst[i] / rs], 1);
    __syncthreads();
    if (threadIdx.x < NR) atomicAdd(&btot[threadIdx.x * 16], h[threadIdx.x]);  // padded: 1 counter / 64B
}

__global__ void k_bscan(const int* __restrict__ btot, int* __restrict__ bstart,
                        int* __restrict__ bcnt, int* __restrict__ bcur) {
    if (threadIdx.x == 0 && blockIdx.x == 0) {
        int acc = 0;
        for (int r = 0; r < NR; ++r) {
            int c = btot[r * 16];
            bstart[r] = acc; bcnt[r] = c; bcur[r * 16] = acc;
            acc += c;
        }
    }
}

__global__ void k_bscatter(const int* __restrict__ src, const int* __restrict__ dst,
                           int* __restrict__ bcur, unsigned* __restrict__ packed,
                           int e, int rs) {
    __shared__ int h[NR], cur[NR];
    int c0 = blockIdx.x * CHUNK;
    int c1 = min(c0 + CHUNK, e);
    if (threadIdx.x < NR) h[threadIdx.x] = 0;
    __syncthreads();
    for (int i = c0 + threadIdx.x; i < c1; i += blockDim.x)
        atomicAdd(&h[dst[i] / rs], 1);
    __syncthreads();
    if (threadIdx.x < NR)
        cur[threadIdx.x] = atomicAdd(&bcur[threadIdx.x * 16], h[threadIdx.x]);
    __syncthreads();
    for (int i = c0 + threadIdx.x; i < c1; i += blockDim.x) {
        int d = dst[i];
        int r = d / rs;
        int slot = atomicAdd(&cur[r], 1);
        packed[slot] = ((unsigned)src[i] << 13) | (unsigned)(d - r * rs);
    }
}

__global__ void k_deg(const unsigned* __restrict__ packed, const int* __restrict__ bstart,
                      const int* __restrict__ bcnt, int* __restrict__ ideg, int rs) {
    __shared__ int acc[RS_MAX];
    int r = blockIdx.y, b = blockIdx.x;
    for (int t = threadIdx.x; t < rs; t += blockDim.x) acc[t] = 0;
    __syncthreads();
    int c = bcnt[r], base = bstart[r];
    int per = (c + gridDim.x - 1) / gridDim.x;
    int lo = b * per, hi = min(lo + per, c);
    for (int i = lo + threadIdx.x; i < hi; i += blockDim.x)
        atomicAdd(&acc[packed[base + i] & 8191], 1);
    __syncthreads();
    int nb = r * rs;
    for (int t = threadIdx.x; t < rs; t += blockDim.x)
        if (acc[t]) atomicAdd(&ideg[nb + t], acc[t]);   // coalesced merge
}

__global__ void k_agg1(const unsigned* __restrict__ packed, const int* __restrict__ bstart,
                       const int* __restrict__ bcnt, const float2* __restrict__ px,
                       float* __restrict__ Pf, int rs) {
    __shared__ float acc[2 * RS_MAX];   // 51.2 KB
    int r = blockIdx.y, b = blockIdx.x;
    for (int t = threadIdx.x; t < 2 * rs; t += blockDim.x) acc[t] = 0.f;
    __syncthreads();
    int c = bcnt[r], base = bstart[r];
    int per = (c + gridDim.x - 1) / gridDim.x;
    int lo = b * per, hi = min(lo + per, c);
    for (int i = lo + threadIdx.x; i < hi; i += blockDim.x) {
        unsigned k = packed[base + i];
        float2 v = px[k >> 13];
        int dl = k & 8191;
        atomicAdd(&acc[2 * dl], v.x);       // ds_add_f32, per-CU
        atomicAdd(&acc[2 * dl + 1], v.y);
    }
    __syncthreads();
    int nb = r * rs * 2;
    for (int t = threadIdx.x; t < 2 * rs; t += blockDim.x)
        if (acc[t] != 0.f) atomicAdd(&Pf[nb + t], acc[t]);   // coalesced merge
}

__global__ void k_agg2(const unsigned* __restrict__ packed, const int* __restrict__ bstart,
                       const int* __restrict__ bcnt, const float* __restrict__ s,
                       float* __restrict__ S, int rs) {
    __shared__ float acc[RS_MAX];
    int r = blockIdx.y, b = blockIdx.x;
    for (int t = threadIdx.x; t < rs; t += blockDim.x) acc[t] = 0.f;
    __syncthreads();
    int c = bcnt[r], base = bstart[r];
    int per = (c + gridDim.x - 1) / gridDim.x;
    int lo = b * per, hi = min(lo + per, c);
    for (int i = lo + threadIdx.x; i < hi; i += blockDim.x) {
        unsigned k = packed[base + i];
        atomicAdd(&acc[k & 8191], s[k >> 13]);
    }
    __syncthreads();
    int nb = r * rs;
    for (int t = threadIdx.x; t < rs; t += blockDim.x)
        if (acc[t] != 0.f) atomicAdd(&S[nb + t], acc[t]);
}

// ---------------- fallback path (round-2 style) ----------------

__global__ void f_zero(int* __restrict__ ideg, float2* __restrict__ P, int n) {
    int i = blockIdx.x * blockDim.x + threadIdx.x;
    if (i < n) { ideg[i] = 0; P[i] = make_float2(0.f, 0.f); }
}
__global__ void f_count(const int* __restrict__ dst, int* __restrict__ ideg, int e) {
    int i = blockIdx.x * blockDim.x + threadIdx.x;
    if (i < e) atomicAdd(&ideg[dst[i]], 1);
}
__global__ void f_scatter_px(const int* __restrict__ src, const int* __restrict__ dst,
                             const float2* __restrict__ px, float* __restrict__ Pf, int e) {
    int i = blockIdx.x * blockDim.x + threadIdx.x;
    if (i >= e) return;
    int sidx = src[i], d = dst[i];
    float2 v = px[sidx];
    atomicAdd(&Pf[2 * d], v.x);
    atomicAdd(&Pf[2 * d + 1], v.y);
}
__global__ void f_scatter_s(const int* __restrict__ src, const int* __restrict__ dst,
                            const float* __restrict__ s, float* __restrict__ S, int e) {
    int i = blockIdx.x * blockDim.x + threadIdx.x;
    if (i < e) atomicAdd(&S[dst[i]], s[src[i]]);
}

// ---------------- launch ----------------

extern "C" void kernel_launch(void* const* d_in, const int* in_sizes, int n_in,
                              void* d_out, int out_size, void* d_ws, size_t ws_size,
                              hipStream_t stream) {
    const float* x  = (const float*)d_in[0];
    const int*   ei = (const int*)d_in[1];
    const float* W1 = (const float*)d_in[2];
    const float* b1 = (const float*)d_in[3];
    const float* W2 = (const float*)d_in[4];
    const float* b2 = (const float*)d_in[5];
    float* out = (float*)d_out;

    int n = in_sizes[0] / 2;   // 100000
    int e = in_sizes[1] / 2;   // 2560000
    const int* src = ei;
    const int* dst = ei + e;
    int rs = (n + NR - 1) / NR;   // 6250

    char* ws = (char*)d_ws;
    auto align = [](size_t v) { return (v + 255) & ~(size_t)255; };
    size_t off = 0;
    int*    ideg = (int*)   (ws + off); off = align(off + (size_t)n * 4);
    float*  dinv = (float*) (ws + off); off = align(off + (size_t)n * 4);
    float2* px   = (float2*)(ws + off); off = align(off + (size_t)n * 8);
    float2* P    = (float2*)(ws + off); off = align(off + (size_t)n * 8);
    float*  s    = (float*) (ws + off); off = align(off + (size_t)n * 4);
    float*  S    = (float*) (ws + off); off = align(off + (size_t)n * 4);
    int*    bstart = (int*)(ws + off); off = align(off + NR * 4);
    int*    bcnt   = (int*)(ws + off); off = align(off + NR * 4);
    int*    btot   = (int*)(ws + off); off = align(off + NR * 16 * 4);
    int*    bcur   = (int*)(ws + off); off = align(off + NR * 16 * 4);
    unsigned* packed = (unsigned*)(ws + off);
    size_t need = off + (size_t)e * 4;

    const int B = 256;
    int gn = (n + B - 1) / B, ge = (e + B - 1) / B;

    bool fast = (need <= ws_size) && (rs <= RS_MAX) && (rs <= 8192) && (n <= (1 << 19));

    if (fast) {
        dim3 ag(AGG_BLKS, NR);
        k_init    <<<gn, B, 0, stream>>>(ideg, (float*)P, btot, n);
        k_bcount  <<<256, B, 0, stream>>>(dst, btot, e, rs);
        k_bscan   <<<1, 64, 0, stream>>>(btot, bstart, bcnt, bcur);
        k_bscatter<<<(e + CHUNK - 1) / CHUNK, B, 0, stream>>>(src, dst, bcur, packed, e, rs);
        k_deg     <<<ag, 1024, 0, stream>>>(packed, bstart, bcnt, ideg, rs);
        k_px      <<<gn, B, 0, stream>>>((const float2*)x, ideg, dinv, px, n);
        k_agg1    <<<ag, 1024, 0, stream>>>(packed, bstart, bcnt, px, (float*)P, rs);
        k_node    <<<gn, B, 0, stream>>>(px, P, dinv, W1, b1, W2, s, S, n);
        k_agg2    <<<ag, 1024, 0, stream>>>(packed, bstart, bcnt, s, S, rs);
        k_out     <<<gn, B, 0, stream>>>(S, dinv, b2, out, n);
    } else {
        f_zero      <<<gn, B, 0, stream>>>(ideg, P, n);
        f_count     <<<ge, B, 0, stream>>>(dst, ideg, e);
        k_px        <<<gn, B, 0, stream>>>((const float2*)x, ideg, dinv, px, n);
        f_scatter_px<<<ge, B, 0, stream>>>(src, dst, px, (float*)P, e);
        k_node      <<<gn, B, 0, stream>>>(px, P, dinv, W1, b1, W2, s, S, n);
        f_scatter_s <<<ge, B, 0, stream>>>(src, dst, s, S, e);
        k_out       <<<gn, B, 0, stream>>>(S, dinv, b2, out, n);
    }
}

// Round 4
// 125.415 us; speedup vs baseline: 4.4253x; 1.0778x over previous
//
#include <hip/hip_runtime.h>

// 2-layer GCN, rank-2 factorization + dst-range bucketing + LDS aggregation.
// R4: NR 16->32 (half LDS per block, 2 blocks/CU -> 32 waves/CU occupancy),
//     x2 unrolled gather loops for MLP. Merge-atomic traffic unchanged.

#define NR 32
#define RS_MAX 3200
#define AGG_BLKS 16
#define CHUNK 4096
#define DBITS 12
#define DMASK 4095

// ---------------- shared small kernels ----------------

__global__ void k_px(const float2* __restrict__ x, const int* __restrict__ ideg,
                     float* __restrict__ dinv, float2* __restrict__ px, int n) {
    int i = blockIdx.x * blockDim.x + threadIdx.x;
    if (i >= n) return;
    float d = rsqrtf((float)(1 + ideg[i]));
    dinv[i] = d;
    float2 xv = x[i];
    px[i] = make_float2(d * xv.x, d * xv.y);
}

__global__ void k_node(const float2* __restrict__ px, const float2* __restrict__ P,
                       const float* __restrict__ dinv,
                       const float* __restrict__ W1, const float* __restrict__ b1,
                       const float* __restrict__ W2,
                       float* __restrict__ s, float* __restrict__ S, int n) {
    int i = blockIdx.x * blockDim.x + threadIdx.x;
    if (i >= n) return;
    float d = dinv[i];
    float2 v = px[i], p = P[i];
    float ax = v.x + p.x, ay = v.y + p.y;
    float dot = 0.f;
#pragma unroll
    for (int j = 0; j < 32; ++j) {
        float acc = fmaf(ax, W1[j], ay * W1[32 + j]);
        float h = fmaxf(fmaf(d, acc, b1[j]), 0.f);
        dot = fmaf(h, W2[j], dot);
    }
    float sv = d * dot;
    s[i] = sv;
    S[i] = sv;   // self-loop term for layer 2
}

__global__ void k_out(const float* __restrict__ S, const float* __restrict__ dinv,
                      const float* __restrict__ b2, float* __restrict__ out, int n) {
    int i = blockIdx.x * blockDim.x + threadIdx.x;
    if (i < n) out[i] = dinv[i] * S[i] + b2[0];
}

// ---------------- fast path: bucketed LDS aggregation ----------------

__global__ void k_init(int* __restrict__ ideg, float* __restrict__ Pf,
                       int* __restrict__ btot, int n) {
    int i = blockIdx.x * blockDim.x + threadIdx.x;
    if (i < n) { ideg[i] = 0; Pf[2 * i] = 0.f; Pf[2 * i + 1] = 0.f; }
    if (i < NR * 16) btot[i] = 0;
}

__global__ void k_bcount(const int* __restrict__ dst, int* __restrict__ btot,
                         int e, int rs) {
    __shared__ int h[NR];
    if (threadIdx.x < NR) h[threadIdx.x] = 0;
    __syncthreads();
    for (int i = blockIdx.x * blockDim.x + threadIdx.x; i < e; i += gridDim.x * blockDim.x)
        atomicAdd(&h[dst[i] / rs], 1);
    __syncthreads();
    if (threadIdx.x < NR) atomicAdd(&btot[threadIdx.x * 16], h[threadIdx.x]);  // padded
}

__global__ void k_bscan(const int* __restrict__ btot, int* __restrict__ bstart,
                        int* __restrict__ bcnt, int* __restrict__ bcur) {
    if (threadIdx.x == 0 && blockIdx.x == 0) {
        int acc = 0;
        for (int r = 0; r < NR; ++r) {
            int c = btot[r * 16];
            bstart[r] = acc; bcnt[r] = c; bcur[r * 16] = acc;
            acc += c;
        }
    }
}

__global__ void k_bscatter(const int* __restrict__ src, const int* __restrict__ dst,
                           int* __restrict__ bcur, unsigned* __restrict__ packed,
                           int e, int rs) {
    __shared__ int h[NR], cur[NR];
    int c0 = blockIdx.x * CHUNK;
    int c1 = min(c0 + CHUNK, e);
    if (threadIdx.x < NR) h[threadIdx.x] = 0;
    __syncthreads();
    for (int i = c0 + threadIdx.x; i < c1; i += blockDim.x)
        atomicAdd(&h[dst[i] / rs], 1);
    __syncthreads();
    if (threadIdx.x < NR)
        cur[threadIdx.x] = atomicAdd(&bcur[threadIdx.x * 16], h[threadIdx.x]);
    __syncthreads();
    for (int i = c0 + threadIdx.x; i < c1; i += blockDim.x) {
        int d = dst[i];
        int r = d / rs;
        int slot = atomicAdd(&cur[r], 1);
        packed[slot] = ((unsigned)src[i] << DBITS) | (unsigned)(d - r * rs);
    }
}

__global__ __launch_bounds__(1024, 2)
void k_deg(const unsigned* __restrict__ packed, const int* __restrict__ bstart,
           const int* __restrict__ bcnt, int* __restrict__ ideg, int rs) {
    __shared__ int acc[RS_MAX];
    int r = blockIdx.y, b = blockIdx.x;
    for (int t = threadIdx.x; t < rs; t += blockDim.x) acc[t] = 0;
    __syncthreads();
    int c = bcnt[r], base = bstart[r];
    int per = (c + gridDim.x - 1) / gridDim.x;
    int lo = b * per, hi = min(lo + per, c);
    int step = blockDim.x;
    int i = lo + threadIdx.x;
    for (; i + step < hi; i += 2 * step) {
        unsigned k0 = packed[base + i];
        unsigned k1 = packed[base + i + step];
        atomicAdd(&acc[k0 & DMASK], 1);
        atomicAdd(&acc[k1 & DMASK], 1);
    }
    for (; i < hi; i += step) atomicAdd(&acc[packed[base + i] & DMASK], 1);
    __syncthreads();
    int nb = r * rs;
    for (int t = threadIdx.x; t < rs; t += blockDim.x)
        if (acc[t]) atomicAdd(&ideg[nb + t], acc[t]);   // coalesced merge
}

__global__ __launch_bounds__(1024, 2)
void k_agg1(const unsigned* __restrict__ packed, const int* __restrict__ bstart,
            const int* __restrict__ bcnt, const float2* __restrict__ px,
            float* __restrict__ Pf, int rs) {
    __shared__ float acc[2 * RS_MAX];   // 25.6 KB
    int r = blockIdx.y, b = blockIdx.x;
    for (int t = threadIdx.x; t < 2 * rs; t += blockDim.x) acc[t] = 0.f;
    __syncthreads();
    int c = bcnt[r], base = bstart[r];
    int per = (c + gridDim.x - 1) / gridDim.x;
    int lo = b * per, hi = min(lo + per, c);
    int step = blockDim.x;
    int i = lo + threadIdx.x;
    for (; i + step < hi; i += 2 * step) {
        unsigned k0 = packed[base + i];
        unsigned k1 = packed[base + i + step];
        float2 v0 = px[k0 >> DBITS];
        float2 v1 = px[k1 >> DBITS];
        int d0 = (k0 & DMASK) * 2, d1 = (k1 & DMASK) * 2;
        atomicAdd(&acc[d0], v0.x);
        atomicAdd(&acc[d0 + 1], v0.y);
        atomicAdd(&acc[d1], v1.x);
        atomicAdd(&acc[d1 + 1], v1.y);
    }
    for (; i < hi; i += step) {
        unsigned k = packed[base + i];
        float2 v = px[k >> DBITS];
        int dl = (k & DMASK) * 2;
        atomicAdd(&acc[dl], v.x);
        atomicAdd(&acc[dl + 1], v.y);
    }
    __syncthreads();
    int nb = r * rs * 2;
    for (int t = threadIdx.x; t < 2 * rs; t += blockDim.x)
        if (acc[t] != 0.f) atomicAdd(&Pf[nb + t], acc[t]);   // coalesced merge
}

__global__ __launch_bounds__(1024, 2)
void k_agg2(const unsigned* __restrict__ packed, const int* __restrict__ bstart,
            const int* __restrict__ bcnt, const float* __restrict__ s,
            float* __restrict__ S, int rs) {
    __shared__ float acc[RS_MAX];
    int r = blockIdx.y, b = blockIdx.x;
    for (int t = threadIdx.x; t < rs; t += blockDim.x) acc[t] = 0.f;
    __syncthreads();
    int c = bcnt[r], base = bstart[r];
    int per = (c + gridDim.x - 1) / gridDim.x;
    int lo = b * per, hi = min(lo + per, c);
    int step = blockDim.x;
    int i = lo + threadIdx.x;
    for (; i + step < hi; i += 2 * step) {
        unsigned k0 = packed[base + i];
        unsigned k1 = packed[base + i + step];
        float v0 = s[k0 >> DBITS];
        float v1 = s[k1 >> DBITS];
        atomicAdd(&acc[k0 & DMASK], v0);
        atomicAdd(&acc[k1 & DMASK], v1);
    }
    for (; i < hi; i += step) {
        unsigned k = packed[base + i];
        atomicAdd(&acc[k & DMASK], s[k >> DBITS]);
    }
    __syncthreads();
    int nb = r * rs;
    for (int t = threadIdx.x; t < rs; t += blockDim.x)
        if (acc[t] != 0.f) atomicAdd(&S[nb + t], acc[t]);
}

// ---------------- fallback path (round-2 style) ----------------

__global__ void f_zero(int* __restrict__ ideg, float2* __restrict__ P, int n) {
    int i = blockIdx.x * blockDim.x + threadIdx.x;
    if (i < n) { ideg[i] = 0; P[i] = make_float2(0.f, 0.f); }
}
__global__ void f_count(const int* __restrict__ dst, int* __restrict__ ideg, int e) {
    int i = blockIdx.x * blockDim.x + threadIdx.x;
    if (i < e) atomicAdd(&ideg[dst[i]], 1);
}
__global__ void f_scatter_px(const int* __restrict__ src, const int* __restrict__ dst,
                             const float2* __restrict__ px, float* __restrict__ Pf, int e) {
    int i = blockIdx.x * blockDim.x + threadIdx.x;
    if (i >= e) return;
    int sidx = src[i], d = dst[i];
    float2 v = px[sidx];
    atomicAdd(&Pf[2 * d], v.x);
    atomicAdd(&Pf[2 * d + 1], v.y);
}
__global__ void f_scatter_s(const int* __restrict__ src, const int* __restrict__ dst,
                            const float* __restrict__ s, float* __restrict__ S, int e) {
    int i = blockIdx.x * blockDim.x + threadIdx.x;
    if (i < e) atomicAdd(&S[dst[i]], s[src[i]]);
}

// ---------------- launch ----------------

extern "C" void kernel_launch(void* const* d_in, const int* in_sizes, int n_in,
                              void* d_out, int out_size, void* d_ws, size_t ws_size,
                              hipStream_t stream) {
    const float* x  = (const float*)d_in[0];
    const int*   ei = (const int*)d_in[1];
    const float* W1 = (const float*)d_in[2];
    const float* b1 = (const float*)d_in[3];
    const float* W2 = (const float*)d_in[4];
    const float* b2 = (const float*)d_in[5];
    float* out = (float*)d_out;

    int n = in_sizes[0] / 2;   // 100000
    int e = in_sizes[1] / 2;   // 2560000
    const int* src = ei;
    const int* dst = ei + e;
    int rs = (n + NR - 1) / NR;   // 3125

    char* ws = (char*)d_ws;
    auto align = [](size_t v) { return (v + 255) & ~(size_t)255; };
    size_t off = 0;
    int*    ideg = (int*)   (ws + off); off = align(off + (size_t)n * 4);
    float*  dinv = (float*) (ws + off); off = align(off + (size_t)n * 4);
    float2* px   = (float2*)(ws + off); off = align(off + (size_t)n * 8);
    float2* P    = (float2*)(ws + off); off = align(off + (size_t)n * 8);
    float*  s    = (float*) (ws + off); off = align(off + (size_t)n * 4);
    float*  S    = (float*) (ws + off); off = align(off + (size_t)n * 4);
    int*    bstart = (int*)(ws + off); off = align(off + NR * 4);
    int*    bcnt   = (int*)(ws + off); off = align(off + NR * 4);
    int*    btot   = (int*)(ws + off); off = align(off + NR * 16 * 4);
    int*    bcur   = (int*)(ws + off); off = align(off + NR * 16 * 4);
    unsigned* packed = (unsigned*)(ws + off);
    size_t need = off + (size_t)e * 4;

    const int B = 256;
    int gn = (n + B - 1) / B, ge = (e + B - 1) / B;

    bool fast = (need <= ws_size) && (rs <= RS_MAX) && (rs <= DMASK + 1) &&
                (n <= (1 << (31 - DBITS)));

    if (fast) {
        dim3 ag(AGG_BLKS, NR);
        k_init    <<<gn, B, 0, stream>>>(ideg, (float*)P, btot, n);
        k_bcount  <<<256, B, 0, stream>>>(dst, btot, e, rs);
        k_bscan   <<<1, 64, 0, stream>>>(btot, bstart, bcnt, bcur);
        k_bscatter<<<(e + CHUNK - 1) / CHUNK, B, 0, stream>>>(src, dst, bcur, packed, e, rs);
        k_deg     <<<ag, 1024, 0, stream>>>(packed, bstart, bcnt, ideg, rs);
        k_px      <<<gn, B, 0, stream>>>((const float2*)x, ideg, dinv, px, n);
        k_agg1    <<<ag, 1024, 0, stream>>>(packed, bstart, bcnt, px, (float*)P, rs);
        k_node    <<<gn, B, 0, stream>>>(px, P, dinv, W1, b1, W2, s, S, n);
        k_agg2    <<<ag, 1024, 0, stream>>>(packed, bstart, bcnt, s, S, rs);
        k_out     <<<gn, B, 0, stream>>>(S, dinv, b2, out, n);
    } else {
        f_zero      <<<gn, B, 0, stream>>>(ideg, P, n);
        f_count     <<<ge, B, 0, stream>>>(dst, ideg, e);
        k_px        <<<gn, B, 0, stream>>>((const float2*)x, ideg, dinv, px, n);
        f_scatter_px<<<ge, B, 0, stream>>>(src, dst, px, (float*)P, e);
        k_node      <<<gn, B, 0, stream>>>(px, P, dinv, W1, b1, W2, s, S, n);
        f_scatter_s <<<ge, B, 0, stream>>>(src, dst, s, S, e);
        k_out       <<<gn, B, 0, stream>>>(S, dinv, b2, out, n);
    }
}

// Round 5
// 107.107 us; speedup vs baseline: 5.1817x; 1.1709x over previous
//
#include <hip/hip_runtime.h>

// 2-layer GCN, rank-2 factorization + dst-range bucketing + LDS aggregation.
// R5: uint4 edge-stream loads (4x gather MLP), atomic-free merges via
//     per-subblock partials summed in consumer kernels, int4 stream reads.

#define NR 32
#define RS_MAX 3200
#define AGG_BLKS 16
#define CHUNK 4096
#define DBITS 12
#define DMASK 4095

// ---------------- node-local kernels (fused partial merges) ----------------

__global__ void k_px(const float2* __restrict__ x, const int* __restrict__ pdeg,
                     float* __restrict__ dinv, float2* __restrict__ px, int n) {
    int i = blockIdx.x * blockDim.x + threadIdx.x;
    if (i >= n) return;
    int deg = 1;  // self-loop
#pragma unroll
    for (int b = 0; b < AGG_BLKS; ++b) deg += pdeg[b * n + i];
    float d = rsqrtf((float)deg);
    dinv[i] = d;
    float2 xv = x[i];
    px[i] = make_float2(d * xv.x, d * xv.y);
}

__global__ void k_node(const float2* __restrict__ px, const float2* __restrict__ pP,
                       const float* __restrict__ dinv,
                       const float* __restrict__ W1, const float* __restrict__ b1,
                       const float* __restrict__ W2, float* __restrict__ s, int n) {
    int i = blockIdx.x * blockDim.x + threadIdx.x;
    if (i >= n) return;
    float2 v = px[i];
    float ax = v.x, ay = v.y;
#pragma unroll
    for (int b = 0; b < AGG_BLKS; ++b) {
        float2 p = pP[b * n + i];
        ax += p.x; ay += p.y;
    }
    float d = dinv[i];
    float dot = 0.f;
#pragma unroll
    for (int j = 0; j < 32; ++j) {
        float acc = fmaf(ax, W1[j], ay * W1[32 + j]);
        float h = fmaxf(fmaf(d, acc, b1[j]), 0.f);
        dot = fmaf(h, W2[j], dot);
    }
    s[i] = d * dot;
}

__global__ void k_out(const float* __restrict__ s, const float* __restrict__ ps,
                      const float* __restrict__ dinv, const float* __restrict__ b2,
                      float* __restrict__ out, int n) {
    int i = blockIdx.x * blockDim.x + threadIdx.x;
    if (i >= n) return;
    float acc = s[i];  // self-loop
#pragma unroll
    for (int b = 0; b < AGG_BLKS; ++b) acc += ps[b * n + i];
    out[i] = dinv[i] * acc + b2[0];
}

// ---------------- bucketing ----------------

__global__ void k_bcount(const int* __restrict__ dst, int* __restrict__ btot,
                         int e, int rs) {
    __shared__ int h[NR];
    if (threadIdx.x < NR) h[threadIdx.x] = 0;
    __syncthreads();
    int eq = e >> 2;
    const int4* d4 = (const int4*)dst;
    for (int i = blockIdx.x * blockDim.x + threadIdx.x; i < eq; i += gridDim.x * blockDim.x) {
        int4 v = d4[i];
        atomicAdd(&h[v.x / rs], 1);
        atomicAdd(&h[v.y / rs], 1);
        atomicAdd(&h[v.z / rs], 1);
        atomicAdd(&h[v.w / rs], 1);
    }
    if (blockIdx.x == 0 && threadIdx.x == 0)
        for (int i = eq * 4; i < e; ++i) atomicAdd(&h[dst[i] / rs], 1);
    __syncthreads();
    if (threadIdx.x < NR) atomicAdd(&btot[threadIdx.x * 16], h[threadIdx.x]);
}

__global__ void k_bscan(const int* __restrict__ btot, int* __restrict__ bstart,
                        int* __restrict__ bcnt, int* __restrict__ bcur) {
    if (threadIdx.x == 0 && blockIdx.x == 0) {
        int acc = 0;
        for (int r = 0; r < NR; ++r) {
            int c = btot[r * 16];
            bstart[r] = acc; bcnt[r] = c; bcur[r * 16] = acc;
            acc += (c + 3) & ~3;   // pad range starts to x4 (uint4 alignment)
        }
    }
}

__global__ void k_bscatter(const int* __restrict__ src, const int* __restrict__ dst,
                           int* __restrict__ bcur, unsigned* __restrict__ packed,
                           int e, int rs) {
    __shared__ int h[NR], cur[NR];
    int c0 = blockIdx.x * CHUNK;
    int c1 = min(c0 + CHUNK, e);
    if (threadIdx.x < NR) h[threadIdx.x] = 0;
    __syncthreads();
    const int4* d4 = (const int4*)dst;
    const int4* s4 = (const int4*)src;
    for (int i = c0 + threadIdx.x * 4; i < c1; i += blockDim.x * 4) {
        if (i + 4 <= c1) {
            int4 v = d4[i >> 2];
            atomicAdd(&h[v.x / rs], 1);
            atomicAdd(&h[v.y / rs], 1);
            atomicAdd(&h[v.z / rs], 1);
            atomicAdd(&h[v.w / rs], 1);
        } else {
            for (int j = i; j < c1; ++j) atomicAdd(&h[dst[j] / rs], 1);
        }
    }
    __syncthreads();
    if (threadIdx.x < NR)
        cur[threadIdx.x] = atomicAdd(&bcur[threadIdx.x * 16], h[threadIdx.x]);
    __syncthreads();
    for (int i = c0 + threadIdx.x * 4; i < c1; i += blockDim.x * 4) {
        if (i + 4 <= c1) {
            int4 dv = d4[i >> 2];
            int4 sv = s4[i >> 2];
            int r0 = dv.x / rs; int t0 = atomicAdd(&cur[r0], 1);
            packed[t0] = ((unsigned)sv.x << DBITS) | (unsigned)(dv.x - r0 * rs);
            int r1 = dv.y / rs; int t1 = atomicAdd(&cur[r1], 1);
            packed[t1] = ((unsigned)sv.y << DBITS) | (unsigned)(dv.y - r1 * rs);
            int r2 = dv.z / rs; int t2 = atomicAdd(&cur[r2], 1);
            packed[t2] = ((unsigned)sv.z << DBITS) | (unsigned)(dv.z - r2 * rs);
            int r3 = dv.w / rs; int t3 = atomicAdd(&cur[r3], 1);
            packed[t3] = ((unsigned)sv.w << DBITS) | (unsigned)(dv.w - r3 * rs);
        } else {
            for (int j = i; j < c1; ++j) {
                int d = dst[j];
                int r = d / rs;
                int slot = atomicAdd(&cur[r], 1);
                packed[slot] = ((unsigned)src[j] << DBITS) | (unsigned)(d - r * rs);
            }
        }
    }
}

// ---------------- LDS aggregations -> partials (no global atomics) ----------

__global__ __launch_bounds__(1024, 8)
void k_deg(const unsigned* __restrict__ packed, const int* __restrict__ bstart,
           const int* __restrict__ bcnt, int* __restrict__ pdeg, int rs, int n) {
    __shared__ int acc[RS_MAX];
    int r = blockIdx.y, b = blockIdx.x;
    int rs_r = min(rs, n - r * rs);
    for (int t = threadIdx.x; t < rs_r; t += blockDim.x) acc[t] = 0;
    __syncthreads();
    int c = bcnt[r], base = bstart[r];
    int q = (c + 3) >> 2;
    int qper = (q + gridDim.x - 1) / gridDim.x;
    int qlo = b * qper, qhi = min(qlo + qper, q);
    const uint4* p4 = (const uint4*)(packed + base);
    for (int j = qlo + threadIdx.x; j < qhi; j += blockDim.x) {
        uint4 v = p4[j];
        int lim = c - j * 4;
        atomicAdd(&acc[v.x & DMASK], 1);
        if (lim > 1) atomicAdd(&acc[v.y & DMASK], 1);
        if (lim > 2) atomicAdd(&acc[v.z & DMASK], 1);
        if (lim > 3) atomicAdd(&acc[v.w & DMASK], 1);
    }
    __syncthreads();
    int nb = b * n + r * rs;
    for (int t = threadIdx.x; t < rs_r; t += blockDim.x) pdeg[nb + t] = acc[t];
}

__global__ __launch_bounds__(1024, 8)
void k_agg1(const unsigned* __restrict__ packed, const int* __restrict__ bstart,
            const int* __restrict__ bcnt, const float2* __restrict__ px,
            float2* __restrict__ pP, int rs, int n) {
    __shared__ float acc[2 * RS_MAX];   // 25.6 KB
    int r = blockIdx.y, b = blockIdx.x;
    int rs_r = min(rs, n - r * rs);
    for (int t = threadIdx.x; t < 2 * rs_r; t += blockDim.x) acc[t] = 0.f;
    __syncthreads();
    int c = bcnt[r], base = bstart[r];
    int q = (c + 3) >> 2;
    int qper = (q + gridDim.x - 1) / gridDim.x;
    int qlo = b * qper, qhi = min(qlo + qper, q);
    const uint4* p4 = (const uint4*)(packed + base);
    int nm1 = n - 1;
    for (int j = qlo + threadIdx.x; j < qhi; j += blockDim.x) {
        uint4 v = p4[j];
        // clamp indices from (possibly garbage) pad lanes; issue all 4 gathers up front
        int i0 = (int)(v.x >> DBITS);
        int i1 = min((int)(v.y >> DBITS), nm1);
        int i2 = min((int)(v.z >> DBITS), nm1);
        int i3 = min((int)(v.w >> DBITS), nm1);
        float2 g0 = px[i0], g1 = px[i1], g2 = px[i2], g3 = px[i3];
        int lim = c - j * 4;
        int d0 = (v.x & DMASK) * 2;
        atomicAdd(&acc[d0], g0.x); atomicAdd(&acc[d0 + 1], g0.y);
        if (lim > 1) { int d1 = (v.y & DMASK) * 2; atomicAdd(&acc[d1], g1.x); atomicAdd(&acc[d1 + 1], g1.y); }
        if (lim > 2) { int d2 = (v.z & DMASK) * 2; atomicAdd(&acc[d2], g2.x); atomicAdd(&acc[d2 + 1], g2.y); }
        if (lim > 3) { int d3 = (v.w & DMASK) * 2; atomicAdd(&acc[d3], g3.x); atomicAdd(&acc[d3 + 1], g3.y); }
    }
    __syncthreads();
    int nb = b * n + r * rs;
    for (int t = threadIdx.x; t < rs_r; t += blockDim.x)
        pP[nb + t] = make_float2(acc[2 * t], acc[2 * t + 1]);
}

__global__ __launch_bounds__(1024, 8)
void k_agg2(const unsigned* __restrict__ packed, const int* __restrict__ bstart,
            const int* __restrict__ bcnt, const float* __restrict__ s,
            float* __restrict__ ps, int rs, int n) {
    __shared__ float acc[RS_MAX];
    int r = blockIdx.y, b = blockIdx.x;
    int rs_r = min(rs, n - r * rs);
    for (int t = threadIdx.x; t < rs_r; t += blockDim.x) acc[t] = 0.f;
    __syncthreads();
    int c = bcnt[r], base = bstart[r];
    int q = (c + 3) >> 2;
    int qper = (q + gridDim.x - 1) / gridDim.x;
    int qlo = b * qper, qhi = min(qlo + qper, q);
    const uint4* p4 = (const uint4*)(packed + base);
    int nm1 = n - 1;
    for (int j = qlo + threadIdx.x; j < qhi; j += blockDim.x) {
        uint4 v = p4[j];
        int i0 = (int)(v.x >> DBITS);
        int i1 = min((int)(v.y >> DBITS), nm1);
        int i2 = min((int)(v.z >> DBITS), nm1);
        int i3 = min((int)(v.w >> DBITS), nm1);
        float g0 = s[i0], g1 = s[i1], g2 = s[i2], g3 = s[i3];
        int lim = c - j * 4;
        atomicAdd(&acc[v.x & DMASK], g0);
        if (lim > 1) atomicAdd(&acc[v.y & DMASK], g1);
        if (lim > 2) atomicAdd(&acc[v.z & DMASK], g2);
        if (lim > 3) atomicAdd(&acc[v.w & DMASK], g3);
    }
    __syncthreads();
    int nb = b * n + r * rs;
    for (int t = threadIdx.x; t < rs_r; t += blockDim.x) ps[nb + t] = acc[t];
}

// ---------------- fallback path (round-2 style) ----------------

__global__ void f_zero(int* __restrict__ ideg, float2* __restrict__ P, int n) {
    int i = blockIdx.x * blockDim.x + threadIdx.x;
    if (i < n) { ideg[i] = 0; P[i] = make_float2(0.f, 0.f); }
}
__global__ void f_count(const int* __restrict__ dst, int* __restrict__ ideg, int e) {
    int i = blockIdx.x * blockDim.x + threadIdx.x;
    if (i < e) atomicAdd(&ideg[dst[i]], 1);
}
__global__ void f_px(const float2* __restrict__ x, const int* __restrict__ ideg,
                     float* __restrict__ dinv, float2* __restrict__ px, int n) {
    int i = blockIdx.x * blockDim.x + threadIdx.x;
    if (i >= n) return;
    float d = rsqrtf((float)(1 + ideg[i]));
    dinv[i] = d;
    float2 xv = x[i];
    px[i] = make_float2(d * xv.x, d * xv.y);
}
__global__ void f_scatter_px(const int* __restrict__ src, const int* __restrict__ dst,
                             const float2* __restrict__ px, float* __restrict__ Pf, int e) {
    int i = blockIdx.x * blockDim.x + threadIdx.x;
    if (i >= e) return;
    int sidx = src[i], d = dst[i];
    float2 v = px[sidx];
    atomicAdd(&Pf[2 * d], v.x);
    atomicAdd(&Pf[2 * d + 1], v.y);
}
__global__ void f_node(const float2* __restrict__ px, const float2* __restrict__ P,
                       const float* __restrict__ dinv,
                       const float* __restrict__ W1, const float* __restrict__ b1,
                       const float* __restrict__ W2,
                       float* __restrict__ s, float* __restrict__ S, int n) {
    int i = blockIdx.x * blockDim.x + threadIdx.x;
    if (i >= n) return;
    float d = dinv[i];
    float2 v = px[i], p = P[i];
    float ax = v.x + p.x, ay = v.y + p.y;
    float dot = 0.f;
#pragma unroll
    for (int j = 0; j < 32; ++j) {
        float acc = fmaf(ax, W1[j], ay * W1[32 + j]);
        float h = fmaxf(fmaf(d, acc, b1[j]), 0.f);
        dot = fmaf(h, W2[j], dot);
    }
    float sv = d * dot;
    s[i] = sv;
    S[i] = sv;
}
__global__ void f_scatter_s(const int* __restrict__ src, const int* __restrict__ dst,
                            const float* __restrict__ s, float* __restrict__ S, int e) {
    int i = blockIdx.x * blockDim.x + threadIdx.x;
    if (i < e) atomicAdd(&S[dst[i]], s[src[i]]);
}
__global__ void f_out(const float* __restrict__ S, const float* __restrict__ dinv,
                      const float* __restrict__ b2, float* __restrict__ out, int n) {
    int i = blockIdx.x * blockDim.x + threadIdx.x;
    if (i < n) out[i] = dinv[i] * S[i] + b2[0];
}

// ---------------- launch ----------------

extern "C" void kernel_launch(void* const* d_in, const int* in_sizes, int n_in,
                              void* d_out, int out_size, void* d_ws, size_t ws_size,
                              hipStream_t stream) {
    const float* x  = (const float*)d_in[0];
    const int*   ei = (const int*)d_in[1];
    const float* W1 = (const float*)d_in[2];
    const float* b1 = (const float*)d_in[3];
    const float* W2 = (const float*)d_in[4];
    const float* b2 = (const float*)d_in[5];
    float* out = (float*)d_out;

    int n = in_sizes[0] / 2;   // 100000
    int e = in_sizes[1] / 2;   // 2560000
    const int* src = ei;
    const int* dst = ei + e;
    int rs = (n + NR - 1) / NR;   // 3125

    char* ws = (char*)d_ws;
    auto align = [](size_t v) { return (v + 255) & ~(size_t)255; };
    size_t off = 0;
    float*  dinv = (float*) (ws + off); off = align(off + (size_t)n * 4);
    float2* px   = (float2*)(ws + off); off = align(off + (size_t)n * 8);
    float*  s    = (float*) (ws + off); off = align(off + (size_t)n * 4);
    int*    pdeg = (int*)   (ws + off); off = align(off + (size_t)AGG_BLKS * n * 4);
    float2* pP   = (float2*)(ws + off); off = align(off + (size_t)AGG_BLKS * n * 8);
    float*  ps   = (float*) (ws + off); off = align(off + (size_t)AGG_BLKS * n * 4);
    int*    bstart = (int*)(ws + off); off = align(off + NR * 4);
    int*    bcnt   = (int*)(ws + off); off = align(off + NR * 4);
    int*    btot   = (int*)(ws + off);                    // btot + bcur contiguous
    int*    bcur   = btot + NR * 16;   off = align(off + (size_t)NR * 16 * 2 * 4);
    unsigned* packed = (unsigned*)(ws + off);
    size_t need = off + (size_t)(e + 4 * NR) * 4;

    const int B = 256;
    int gn = (n + B - 1) / B, ge = (e + B - 1) / B;

    bool fast = (need <= ws_size) && (rs <= RS_MAX) && (rs <= DMASK + 1) &&
                (n <= (1 << (31 - DBITS)));

    if (fast) {
        dim3 ag(AGG_BLKS, NR);
        hipMemsetAsync(btot, 0, (size_t)NR * 16 * 2 * 4, stream);
        k_bcount  <<<256, B, 0, stream>>>(dst, btot, e, rs);
        k_bscan   <<<1, 64, 0, stream>>>(btot, bstart, bcnt, bcur);
        k_bscatter<<<(e + CHUNK - 1) / CHUNK, B, 0, stream>>>(src, dst, bcur, packed, e, rs);
        k_deg     <<<ag, 1024, 0, stream>>>(packed, bstart, bcnt, pdeg, rs, n);
        k_px      <<<gn, B, 0, stream>>>((const float2*)x, pdeg, dinv, px, n);
        k_agg1    <<<ag, 1024, 0, stream>>>(packed, bstart, bcnt, px, pP, rs, n);
        k_node    <<<gn, B, 0, stream>>>(px, pP, dinv, W1, b1, W2, s, n);
        k_agg2    <<<ag, 1024, 0, stream>>>(packed, bstart, bcnt, s, ps, rs, n);
        k_out     <<<gn, B, 0, stream>>>(s, ps, dinv, b2, out, n);
    } else {
        // reuse partial regions as dense accumulators
        int*   ideg = pdeg;
        float2* P   = pP;
        float* S    = ps;
        f_zero      <<<gn, B, 0, stream>>>(ideg, P, n);
        f_count     <<<ge, B, 0, stream>>>(dst, ideg, e);
        f_px        <<<gn, B, 0, stream>>>((const float2*)x, ideg, dinv, px, n);
        f_scatter_px<<<ge, B, 0, stream>>>(src, dst, px, (float*)P, e);
        f_node      <<<gn, B, 0, stream>>>(px, P, dinv, W1, b1, W2, s, S, n);
        f_scatter_s <<<ge, B, 0, stream>>>(src, dst, s, S, e);
        f_out       <<<gn, B, 0, stream>>>(S, dinv, b2, out, n);
    }
}